// Round 1
// baseline (2642.784 us; speedup 1.0000x reference)
//
#include <hip/hip_runtime.h>
#include <math.h>

constexpr int Bn = 8, Dn = 1024, Tn = 4096, NQn = 32, Kn = 1024, CDn = 8;
constexpr float EPSF = 1e-12f;

// ---------------- prepass 1: normalized codebooks + their squared norms ----
__global__ void prep_cbn_kernel(const float* __restrict__ cb,
                                float* __restrict__ cbn,
                                float* __restrict__ n2) {
  const int idx = blockIdx.x * 256 + threadIdx.x;  // nq*K + k
  if (idx >= NQn * Kn) return;
  const float* row = cb + (size_t)idx * CDn;
  float v[8];
#pragma unroll
  for (int c = 0; c < 8; ++c) v[c] = row[c];
  float s = 0.f;
#pragma unroll
  for (int c = 0; c < 8; ++c) s += v[c] * v[c];
  const float den = fmaxf(sqrtf(s), EPSF);
  float nv[8];
#pragma unroll
  for (int c = 0; c < 8; ++c) nv[c] = v[c] / den;
  float s2 = 0.f;
#pragma unroll
  for (int c = 0; c < 8; ++c) s2 += nv[c] * nv[c];
  float* orow = cbn + (size_t)idx * CDn;
#pragma unroll
  for (int c = 0; c < 8; ++c) orow[c] = nv[c];
  n2[idx] = s2;
}

// ---------------- prepass 2: argmin index for fully-masked positions -------
// masked: residual*mask = 0 -> z_e = b_in[nq] exactly; same idx for all t.
__global__ void prep_midx_kernel(const float* __restrict__ b_in,
                                 const float* __restrict__ cbn,
                                 const float* __restrict__ n2,
                                 int* __restrict__ midx) {
  const int nq = blockIdx.x;
  const int lane = threadIdx.x;  // 64 threads = 1 wave
  const float* bi = b_in + nq * CDn;
  float ze[8];
#pragma unroll
  for (int c = 0; c < 8; ++c) ze[c] = bi[c];
  float s = 0.f;
#pragma unroll
  for (int c = 0; c < 8; ++c) s += ze[c] * ze[c];
  const float den = fmaxf(sqrtf(s), EPSF);
  float enc[8];
#pragma unroll
  for (int c = 0; c < 8; ++c) enc[c] = ze[c] / den;
  float e2 = 0.f;
#pragma unroll
  for (int c = 0; c < 8; ++c) e2 += enc[c] * enc[c];

  const float* CBN = cbn + (size_t)nq * Kn * CDn;
  const float* NN = n2 + (size_t)nq * Kn;
  float bd = 1e30f;
  int bk = 0;
#pragma unroll 4
  for (int mi = 0; mi < 16; ++mi) {
    const int k = (mi << 6) + lane;
    const float4 c0 = *(const float4*)(CBN + (k << 3));
    const float4 c1 = *(const float4*)(CBN + (k << 3) + 4);
    const float nnk = NN[k];
    float dot = c0.x * enc[0];
    dot = fmaf(c0.y, enc[1], dot);
    dot = fmaf(c0.z, enc[2], dot);
    dot = fmaf(c0.w, enc[3], dot);
    dot = fmaf(c1.x, enc[4], dot);
    dot = fmaf(c1.y, enc[5], dot);
    dot = fmaf(c1.z, enc[6], dot);
    dot = fmaf(c1.w, enc[7], dot);
    const float dd = fmaf(-2.f, dot, e2) + nnk;
    if (dd < bd) { bd = dd; bk = k; }
  }
#pragma unroll
  for (int mask = 1; mask <= 32; mask <<= 1) {
    const float od = __shfl_xor(bd, mask);
    const int ok = __shfl_xor(bk, mask);
    const bool take = (od < bd) || (od == bd && ok < bk);
    bd = take ? od : bd;
    bk = take ? ok : bk;
  }
  if (lane == 0) midx[nq] = bk;
}

// ---------------- main kernel ---------------------------------------------
// block = 256 thr = 4 waves; each wave owns 4 consecutive t-columns.
// lane owns d = 256*j + 4*lane + i (j,i in 0..3): r[4 cols][16 d] in VGPRs.
__global__ __launch_bounds__(256, 2) void rvq_main_kernel(
    const float* __restrict__ z, const int* __restrict__ lenp,
    const float* __restrict__ W_in, const float* __restrict__ b_in,
    const float* __restrict__ W_out, const float* __restrict__ b_out,
    const float* __restrict__ cbraw, const float* __restrict__ cbn,
    const float* __restrict__ n2, const int* __restrict__ midx,
    float* __restrict__ out) {
  const int tid = threadIdx.x;
  const int lane = tid & 63;
  const int w = tid >> 6;
  const int blk = blockIdx.x;
  const int b = blk >> 8;      // 256 blocks per batch entry
  const int tb = blk & 255;
  const int t0 = tb << 4;      // 16 t's per block
  const int len = lenp[b];
  const int tcol = t0 + (w << 2);  // this wave's 4 columns: tcol..tcol+3

  float m[4];
#pragma unroll
  for (int cc = 0; cc < 4; ++cc) m[cc] = (tcol + cc < len) ? 1.0f : 0.0f;

  float* qout = out;
  float* idxout = out + (size_t)Bn * Dn * Tn;
  float* lenout = idxout + (size_t)NQn * Bn * Tn;
  if (tb == 0 && tid == 0) lenout[b] = (float)len;

  const size_t zb = (size_t)b * Dn * Tn;
  const bool wave_masked = (tcol >= len);

  float r[4][16];

  if (wave_masked) {
    // residual*mask == 0 throughout; idx is the precomputed constant.
#pragma unroll
    for (int q = 0; q < 16; ++q) { r[0][q] = 0.f; r[1][q] = 0.f; r[2][q] = 0.f; r[3][q] = 0.f; }
#pragma unroll 1
    for (int nq = 0; nq < NQn; ++nq) {
      const float v = (float)midx[nq];
      if (lane == 0) {
        float4 iv; iv.x = v; iv.y = v; iv.z = v; iv.w = v;
        *(float4*)(idxout + (size_t)(nq * Bn + b) * Tn + tcol) = iv;
      }
    }
  } else {
    // init residual = z * mask
#pragma unroll
    for (int j = 0; j < 4; ++j) {
#pragma unroll
      for (int i = 0; i < 4; ++i) {
        const int d = (j << 8) + (lane << 2) + i;
        const float4 zv = *(const float4*)(z + zb + (size_t)d * Tn + tcol);
        r[0][(j << 2) + i] = zv.x * m[0];
        r[1][(j << 2) + i] = zv.y * m[1];
        r[2][(j << 2) + i] = zv.z * m[2];
        r[3][(j << 2) + i] = zv.w * m[3];
      }
    }

    const int b0 = lane & 1, b1 = (lane >> 1) & 1, b2 = (lane >> 2) & 1;

#pragma unroll 1
    for (int nq = 0; nq < NQn; ++nq) {
      const float* Wi = W_in + nq * CDn * Dn;
      const float* bi = b_in + nq * CDn;
      const float* Wo = W_out + nq * Dn * CDn;
      const float* bo = b_out + nq * Dn;
      const float* CBN = cbn + (size_t)nq * Kn * CDn;
      const float* NN = n2 + (size_t)nq * Kn;
      const float* CBR = cbraw + (size_t)nq * Kn * CDn;

      // ---- in_proj: per-lane partials over its 16 d's, all 8 channels ----
      float part[4][8];
#pragma unroll
      for (int cc = 0; cc < 4; ++cc)
#pragma unroll
        for (int c = 0; c < 8; ++c) part[cc][c] = 0.f;
#pragma unroll
      for (int c = 0; c < 8; ++c) {
#pragma unroll
        for (int j = 0; j < 4; ++j) {
          const float4 wv = *(const float4*)(Wi + c * Dn + (j << 8) + (lane << 2));
#pragma unroll
          for (int cc = 0; cc < 4; ++cc) {
            part[cc][c] = fmaf(wv.x, r[cc][(j << 2) + 0], part[cc][c]);
            part[cc][c] = fmaf(wv.y, r[cc][(j << 2) + 1], part[cc][c]);
            part[cc][c] = fmaf(wv.z, r[cc][(j << 2) + 2], part[cc][c]);
            part[cc][c] = fmaf(wv.w, r[cc][(j << 2) + 3], part[cc][c]);
          }
        }
      }
      const float biv = bi[lane & 7];

      // ---- transpose-reduce 8 partials across 64 lanes; normalize --------
      float ef[4][8], e2v[4];
#pragma unroll
      for (int cc = 0; cc < 4; ++cc) {
        float u0, u1, u2, u3, v0, v1, t;
        {
          float k0 = b0 ? part[cc][1] : part[cc][0];
          float s0 = b0 ? part[cc][0] : part[cc][1];
          u0 = k0 + __shfl_xor(s0, 1);
          float k1 = b0 ? part[cc][3] : part[cc][2];
          float s1 = b0 ? part[cc][2] : part[cc][3];
          u1 = k1 + __shfl_xor(s1, 1);
          float k2 = b0 ? part[cc][5] : part[cc][4];
          float s2 = b0 ? part[cc][4] : part[cc][5];
          u2 = k2 + __shfl_xor(s2, 1);
          float k3 = b0 ? part[cc][7] : part[cc][6];
          float s3 = b0 ? part[cc][6] : part[cc][7];
          u3 = k3 + __shfl_xor(s3, 1);
        }
        v0 = (b1 ? u1 : u0) + __shfl_xor(b1 ? u0 : u1, 2);
        v1 = (b1 ? u3 : u2) + __shfl_xor(b1 ? u2 : u3, 2);
        t = (b2 ? v1 : v0) + __shfl_xor(b2 ? v0 : v1, 4);
        t += __shfl_xor(t, 8);
        t += __shfl_xor(t, 16);
        t += __shfl_xor(t, 32);
        const float zec = t + biv;  // lane holds z_e[c = lane&7]
        float nn = zec * zec;
        nn += __shfl_xor(nn, 1);
        nn += __shfl_xor(nn, 2);
        nn += __shfl_xor(nn, 4);
        const float den = fmaxf(sqrtf(nn), EPSF);
        const float ec = zec / den;
        float e2 = ec * ec;
        e2 += __shfl_xor(e2, 1);
        e2 += __shfl_xor(e2, 2);
        e2 += __shfl_xor(e2, 4);
        e2v[cc] = e2;
#pragma unroll
        for (int c = 0; c < 8; ++c) ef[cc][c] = __shfl(ec, c);
      }

      // ---- dist + argmin over K=1024 (lane scans k = mi*64 + lane) -------
      float bdv[4];
      int bkv[4];
#pragma unroll
      for (int cc = 0; cc < 4; ++cc) { bdv[cc] = 1e30f; bkv[cc] = 0; }
#pragma unroll 4
      for (int mi = 0; mi < 16; ++mi) {
        const int k = (mi << 6) + lane;
        const float4 c0 = *(const float4*)(CBN + (k << 3));
        const float4 c1 = *(const float4*)(CBN + (k << 3) + 4);
        const float nnk = NN[k];
#pragma unroll
        for (int cc = 0; cc < 4; ++cc) {
          float dot = c0.x * ef[cc][0];
          dot = fmaf(c0.y, ef[cc][1], dot);
          dot = fmaf(c0.z, ef[cc][2], dot);
          dot = fmaf(c0.w, ef[cc][3], dot);
          dot = fmaf(c1.x, ef[cc][4], dot);
          dot = fmaf(c1.y, ef[cc][5], dot);
          dot = fmaf(c1.z, ef[cc][6], dot);
          dot = fmaf(c1.w, ef[cc][7], dot);
          const float dd = fmaf(-2.f, dot, e2v[cc]) + nnk;
          if (dd < bdv[cc]) { bdv[cc] = dd; bkv[cc] = k; }  // first-min in k
        }
      }
#pragma unroll
      for (int mask = 1; mask <= 32; mask <<= 1) {
#pragma unroll
        for (int cc = 0; cc < 4; ++cc) {
          const float od = __shfl_xor(bdv[cc], mask);
          const int ok = __shfl_xor(bkv[cc], mask);
          const bool take = (od < bdv[cc]) || (od == bdv[cc] && ok < bkv[cc]);
          bdv[cc] = take ? od : bdv[cc];
          bkv[cc] = take ? ok : bkv[cc];
        }
      }
      if (lane == 0) {
        float4 iv;
        iv.x = (float)bkv[0]; iv.y = (float)bkv[1];
        iv.z = (float)bkv[2]; iv.w = (float)bkv[3];
        *(float4*)(idxout + (size_t)(nq * Bn + b) * Tn + tcol) = iv;
      }

      // ---- gather raw codebook rows --------------------------------------
      float zq[4][8];
#pragma unroll
      for (int cc = 0; cc < 4; ++cc) {
        const float4 q0 = *(const float4*)(CBR + (bkv[cc] << 3));
        const float4 q1 = *(const float4*)(CBR + (bkv[cc] << 3) + 4);
        zq[cc][0] = q0.x; zq[cc][1] = q0.y; zq[cc][2] = q0.z; zq[cc][3] = q0.w;
        zq[cc][4] = q1.x; zq[cc][5] = q1.y; zq[cc][6] = q1.z; zq[cc][7] = q1.w;
      }

      // ---- out_proj + residual update ------------------------------------
#pragma unroll
      for (int j = 0; j < 4; ++j) {
        const float4 bov = *(const float4*)(bo + (j << 8) + (lane << 2));
#pragma unroll
        for (int i = 0; i < 4; ++i) {
          const int d = (j << 8) + (lane << 2) + i;
          const float4 w0 = *(const float4*)(Wo + (d << 3));
          const float4 w1 = *(const float4*)(Wo + (d << 3) + 4);
          const float bod = (i == 0) ? bov.x : (i == 1) ? bov.y : (i == 2) ? bov.z : bov.w;
#pragma unroll
          for (int cc = 0; cc < 4; ++cc) {
            float acc = w0.x * zq[cc][0];
            acc = fmaf(w0.y, zq[cc][1], acc);
            acc = fmaf(w0.z, zq[cc][2], acc);
            acc = fmaf(w0.w, zq[cc][3], acc);
            acc = fmaf(w1.x, zq[cc][4], acc);
            acc = fmaf(w1.y, zq[cc][5], acc);
            acc = fmaf(w1.z, zq[cc][6], acc);
            acc = fmaf(w1.w, zq[cc][7], acc);
            const float zo = acc + bod;
            r[cc][(j << 2) + i] = fmaf(-m[cc], zo, r[cc][(j << 2) + i]);
          }
        }
      }
    }  // nq
  }

  // ---- final: qout = (z - residual) * mask (exact 0 for masked cols) -----
  if (wave_masked) {
#pragma unroll
    for (int j = 0; j < 4; ++j) {
#pragma unroll
      for (int i = 0; i < 4; ++i) {
        const int d = (j << 8) + (lane << 2) + i;
        float4 ov; ov.x = 0.f; ov.y = 0.f; ov.z = 0.f; ov.w = 0.f;
        *(float4*)(qout + zb + (size_t)d * Tn + tcol) = ov;
      }
    }
  } else {
#pragma unroll
    for (int j = 0; j < 4; ++j) {
#pragma unroll
      for (int i = 0; i < 4; ++i) {
        const int d = (j << 8) + (lane << 2) + i;
        const float4 zv = *(const float4*)(z + zb + (size_t)d * Tn + tcol);
        float4 ov;
        ov.x = (zv.x - r[0][(j << 2) + i]) * m[0];
        ov.y = (zv.y - r[1][(j << 2) + i]) * m[1];
        ov.z = (zv.z - r[2][(j << 2) + i]) * m[2];
        ov.w = (zv.w - r[3][(j << 2) + i]) * m[3];
        *(float4*)(qout + zb + (size_t)d * Tn + tcol) = ov;
      }
    }
  }
}

extern "C" void kernel_launch(void* const* d_in, const int* in_sizes, int n_in,
                              void* d_out, int out_size, void* d_ws, size_t ws_size,
                              hipStream_t stream) {
  const float* z = (const float*)d_in[0];
  const int* input_length = (const int*)d_in[1];
  const float* W_in = (const float*)d_in[2];
  const float* b_in = (const float*)d_in[3];
  const float* W_out = (const float*)d_in[4];
  const float* b_out = (const float*)d_in[5];
  const float* codebooks = (const float*)d_in[6];
  float* out = (float*)d_out;

  float* wsf = (float*)d_ws;
  float* cbn = wsf;                          // NQ*K*CD floats (1 MB)
  float* n2 = wsf + (size_t)NQn * Kn * CDn;  // NQ*K floats (128 KB)
  int* midx = (int*)(n2 + (size_t)NQn * Kn); // NQ ints

  prep_cbn_kernel<<<(NQn * Kn + 255) / 256, 256, 0, stream>>>(codebooks, cbn, n2);
  prep_midx_kernel<<<NQn, 64, 0, stream>>>(b_in, cbn, n2, midx);
  rvq_main_kernel<<<(Bn * Tn) / 16, 256, 0, stream>>>(
      z, input_length, W_in, b_in, W_out, b_out, codebooks, cbn, n2, midx, out);
}

// Round 3
// 1746.026 us; speedup vs baseline: 1.5136x; 1.5136x over previous
//
#include <hip/hip_runtime.h>
#include <math.h>

constexpr int Bn = 8, Dn = 1024, Tn = 4096, NQn = 32, Kn = 1024, CDn = 8;
constexpr float EPSF = 1e-12f;

// ---- prepass 1: normalized codebooks as half-tables + squared norms -------
__global__ void prep_cbn_kernel(const float* __restrict__ cb,
                                float* __restrict__ cbnA,
                                float* __restrict__ cbnB,
                                float* __restrict__ n2) {
  const int idx = blockIdx.x * 256 + threadIdx.x;  // nq*K + k
  if (idx >= NQn * Kn) return;
  const float* row = cb + (size_t)idx * CDn;
  float v[8];
#pragma unroll
  for (int c = 0; c < 8; ++c) v[c] = row[c];
  float s = 0.f;
#pragma unroll
  for (int c = 0; c < 8; ++c) s += v[c] * v[c];
  const float den = fmaxf(sqrtf(s), EPSF);
  float nv[8];
#pragma unroll
  for (int c = 0; c < 8; ++c) nv[c] = v[c] / den;
  float s2 = 0.f;
#pragma unroll
  for (int c = 0; c < 8; ++c) s2 += nv[c] * nv[c];
#pragma unroll
  for (int c = 0; c < 4; ++c) cbnA[idx * 4 + c] = nv[c];
#pragma unroll
  for (int c = 0; c < 4; ++c) cbnB[idx * 4 + c] = nv[c + 4];
  n2[idx] = s2;
}

// ---- prepass 1b: transpose W_out [nq][d][c] -> [nq][c][d] -----------------
__global__ void prep_wot_kernel(const float* __restrict__ wo,
                                float* __restrict__ wot) {
  const int id = blockIdx.x * 256 + threadIdx.x;  // nq*8192 + d*8 + c
  if (id >= NQn * Dn * CDn) return;
  const int nq = id >> 13;
  const int rem = id & 8191;
  const int d = rem >> 3;
  const int c = rem & 7;
  wot[nq * 8192 + c * 1024 + d] = wo[id];
}

// ---- prepass 2: argmin index for fully-masked positions -------------------
__global__ void prep_midx_kernel(const float* __restrict__ b_in,
                                 const float* __restrict__ cbnA,
                                 const float* __restrict__ cbnB,
                                 const float* __restrict__ n2,
                                 int* __restrict__ midx) {
  const int nq = blockIdx.x;
  const int lane = threadIdx.x;  // 64 threads = 1 wave
  const float* bi = b_in + nq * CDn;
  float ze[8];
#pragma unroll
  for (int c = 0; c < 8; ++c) ze[c] = bi[c];
  float s = 0.f;
#pragma unroll
  for (int c = 0; c < 8; ++c) s += ze[c] * ze[c];
  const float den = fmaxf(sqrtf(s), EPSF);
  float enc[8];
#pragma unroll
  for (int c = 0; c < 8; ++c) enc[c] = ze[c] / den;
  float e2 = 0.f;
#pragma unroll
  for (int c = 0; c < 8; ++c) e2 += enc[c] * enc[c];

  const float* CA = cbnA + (size_t)nq * Kn * 4;
  const float* CB = cbnB + (size_t)nq * Kn * 4;
  const float* NN = n2 + (size_t)nq * Kn;
  float bd = 1e30f;
  int bk = 0;
#pragma unroll 4
  for (int mi = 0; mi < 16; ++mi) {
    const int k = (mi << 6) + lane;
    const float4 c0 = *(const float4*)(CA + (k << 2));
    const float4 c1 = *(const float4*)(CB + (k << 2));
    const float nnk = NN[k];
    float dot = c0.x * enc[0];
    dot = fmaf(c0.y, enc[1], dot);
    dot = fmaf(c0.z, enc[2], dot);
    dot = fmaf(c0.w, enc[3], dot);
    dot = fmaf(c1.x, enc[4], dot);
    dot = fmaf(c1.y, enc[5], dot);
    dot = fmaf(c1.z, enc[6], dot);
    dot = fmaf(c1.w, enc[7], dot);
    const float dd = fmaf(-2.f, dot, e2) + nnk;
    if (dd < bd) { bd = dd; bk = k; }
  }
#pragma unroll
  for (int mask = 1; mask <= 32; mask <<= 1) {
    const float od = __shfl_xor(bd, mask);
    const int ok = __shfl_xor(bk, mask);
    const bool take = (od < bd) || (od == bd && ok < bk);
    bd = take ? od : bd;
    bk = take ? ok : bk;
  }
  if (lane == 0) midx[nq] = bk;
}

// ---------------- main kernel ---------------------------------------------
// block = 512 thr = 8 waves; each wave owns 8 consecutive t-columns (64/blk).
// Per nq: block stages all tables into LDS (plain contiguous copies, no
// swizzle), then each wave computes its cols. All hot LDS reads are
// lane-contiguous 16B (canonical), stride-4B scalar, or uniform broadcast.
__global__ __launch_bounds__(512, 2) void rvq_main_kernel(
    const float* __restrict__ z, const int* __restrict__ lenp,
    const float* __restrict__ W_in, const float* __restrict__ b_in,
    const float* __restrict__ wotg, const float* __restrict__ b_out,
    const float* __restrict__ cbraw, const float* __restrict__ cbnAg,
    const float* __restrict__ cbnBg, const float* __restrict__ n2g,
    const int* __restrict__ midx, float* __restrict__ out) {
  __shared__ __align__(16) float sWi[8192];    // [8 c][1024 d]
  __shared__ __align__(16) float sWoT[8192];   // [8 c][1024 d] (transposed)
  __shared__ __align__(16) float sCBR[8192];   // raw codebook [1024 k][8 c]
  __shared__ __align__(16) float sCBNA[4096];  // [1024 k][c 0..3]
  __shared__ __align__(16) float sCBNB[4096];  // [1024 k][c 4..7]
  __shared__ __align__(16) float sNN[1024];
  __shared__ __align__(16) float sBO[1024];
  __shared__ __align__(16) float sBIall[256];  // all 32 nq x 8 b_in

  const int tid = threadIdx.x;
  const int lane = tid & 63;
  const int w = tid >> 6;
  const int blk = blockIdx.x;
  const int b = blk & 7;  // interleave batches for load balance
  const int tb = blk >> 3;
  const int t0 = tb << 6;  // 64 t's per block
  const int len = lenp[b];

  float* qout = out;
  float* idxout = out + (size_t)Bn * Dn * Tn;
  float* lenout = idxout + (size_t)NQn * Bn * Tn;
  if (tb == 0 && tid == 0) lenout[b] = (float)len;

  const size_t zb = (size_t)b * Dn * Tn;

  // ---- fully-masked block: barrier-free early path ------------------------
  if (t0 >= len) {
    {
      const int nq = tid >> 4;
      const int toff = (tid & 15) << 2;
      const float v = (float)midx[nq];
      float4 iv; iv.x = v; iv.y = v; iv.z = v; iv.w = v;
      *(float4*)(idxout + (size_t)(nq * Bn + b) * Tn + t0 + toff) = iv;
    }
    float4 zv; zv.x = 0.f; zv.y = 0.f; zv.z = 0.f; zv.w = 0.f;
#pragma unroll 4
    for (int it = 0; it < 32; ++it) {
      const int d = (it << 5) + (tid >> 4);
      const int toff = (tid & 15) << 2;
      *(float4*)(qout + zb + (size_t)d * Tn + t0 + toff) = zv;
    }
    return;
  }

  const int tcol = t0 + (w << 3);  // this wave's 8 columns
  float m[8];
#pragma unroll
  for (int cc = 0; cc < 8; ++cc) m[cc] = (tcol + cc < len) ? 1.0f : 0.0f;

  // ---- init residual = z * mask ------------------------------------------
  float r[8][16];
#pragma unroll
  for (int j = 0; j < 4; ++j) {
#pragma unroll
    for (int i = 0; i < 4; ++i) {
      const int d = (j << 8) + (lane << 2) + i;
      const float* zp = z + zb + (size_t)d * Tn + tcol;
      const float4 a0 = *(const float4*)zp;
      const float4 a1 = *(const float4*)(zp + 4);
      const int q = (j << 2) + i;
      r[0][q] = a0.x * m[0]; r[1][q] = a0.y * m[1];
      r[2][q] = a0.z * m[2]; r[3][q] = a0.w * m[3];
      r[4][q] = a1.x * m[4]; r[5][q] = a1.y * m[5];
      r[6][q] = a1.z * m[6]; r[7][q] = a1.w * m[7];
    }
  }

  const int b0 = lane & 1, b1 = (lane >> 1) & 1, b2 = (lane >> 2) & 1;

#pragma unroll 1
  for (int nq = 0; nq < NQn; ++nq) {
    // ---- stage tables into LDS (whole block, plain contiguous copies) ----
    if (nq) __syncthreads();
    {
      const float4* Wi4 = (const float4*)(W_in + (size_t)nq * 8192);
      const float4* WT4 = (const float4*)(wotg + (size_t)nq * 8192);
      const float4* CR4 = (const float4*)(cbraw + (size_t)nq * 8192);
      const float4* CA4 = (const float4*)(cbnAg + (size_t)nq * 4096);
      const float4* CB4 = (const float4*)(cbnBg + (size_t)nq * 4096);
      const float4* NN4 = (const float4*)(n2g + (size_t)nq * 1024);
      const float4* BO4 = (const float4*)(b_out + (size_t)nq * 1024);
#pragma unroll
      for (int qq = 0; qq < 4; ++qq) {
        const int p = tid + (qq << 9);
        ((float4*)sWi)[p] = Wi4[p];
        ((float4*)sWoT)[p] = WT4[p];
        ((float4*)sCBR)[p] = CR4[p];
      }
#pragma unroll
      for (int qq = 0; qq < 2; ++qq) {
        const int p = tid + (qq << 9);
        ((float4*)sCBNA)[p] = CA4[p];
        ((float4*)sCBNB)[p] = CB4[p];
      }
      if (tid < 256) ((float4*)sNN)[tid] = NN4[tid];
      else if (tid < 512) ((float4*)sBO)[tid - 256] = BO4[tid - 256];
      if (nq == 0 && tid < 64) ((float4*)sBIall)[tid] = ((const float4*)b_in)[tid];
    }
    __syncthreads();

    // ---- in_proj: per-lane partials over its 16 d's, all 8 channels ------
    float part[8][8];
#pragma unroll
    for (int cc = 0; cc < 8; ++cc)
#pragma unroll
      for (int c = 0; c < 8; ++c) part[cc][c] = 0.f;
#pragma unroll
    for (int c = 0; c < 8; ++c) {
#pragma unroll
      for (int j = 0; j < 4; ++j) {
        const float4 wv = *(const float4*)(sWi + (c << 10) + (j << 8) + (lane << 2));
#pragma unroll
        for (int cc = 0; cc < 8; ++cc) {
          part[cc][c] = fmaf(wv.x, r[cc][(j << 2) + 0], part[cc][c]);
          part[cc][c] = fmaf(wv.y, r[cc][(j << 2) + 1], part[cc][c]);
          part[cc][c] = fmaf(wv.z, r[cc][(j << 2) + 2], part[cc][c]);
          part[cc][c] = fmaf(wv.w, r[cc][(j << 2) + 3], part[cc][c]);
        }
      }
    }
    const float biv = sBIall[(nq << 3) + (lane & 7)];

    // ---- transpose-reduce 8 partials across 64 lanes; normalize ----------
    float ef[8][8], e2v[8];
#pragma unroll
    for (int cc = 0; cc < 8; ++cc) {
      float u0, u1, u2, u3, v0, v1, t;
      {
        float k0 = b0 ? part[cc][1] : part[cc][0];
        float s0 = b0 ? part[cc][0] : part[cc][1];
        u0 = k0 + __shfl_xor(s0, 1);
        float k1 = b0 ? part[cc][3] : part[cc][2];
        float s1 = b0 ? part[cc][2] : part[cc][3];
        u1 = k1 + __shfl_xor(s1, 1);
        float k2 = b0 ? part[cc][5] : part[cc][4];
        float s2 = b0 ? part[cc][4] : part[cc][5];
        u2 = k2 + __shfl_xor(s2, 1);
        float k3 = b0 ? part[cc][7] : part[cc][6];
        float s3 = b0 ? part[cc][6] : part[cc][7];
        u3 = k3 + __shfl_xor(s3, 1);
      }
      v0 = (b1 ? u1 : u0) + __shfl_xor(b1 ? u0 : u1, 2);
      v1 = (b1 ? u3 : u2) + __shfl_xor(b1 ? u2 : u3, 2);
      t = (b2 ? v1 : v0) + __shfl_xor(b2 ? v0 : v1, 4);
      t += __shfl_xor(t, 8);
      t += __shfl_xor(t, 16);
      t += __shfl_xor(t, 32);
      const float zec = t + biv;  // lane holds z_e[c = lane&7]
      float nn = zec * zec;
      nn += __shfl_xor(nn, 1);
      nn += __shfl_xor(nn, 2);
      nn += __shfl_xor(nn, 4);
      const float den = fmaxf(sqrtf(nn), EPSF);
      const float ec = zec / den;
      float e2 = ec * ec;
      e2 += __shfl_xor(e2, 1);
      e2 += __shfl_xor(e2, 2);
      e2 += __shfl_xor(e2, 4);
      e2v[cc] = e2;
#pragma unroll
      for (int c = 0; c < 8; ++c) ef[cc][c] = __shfl(ec, c);
    }

    // ---- dist + argmin over K=1024 (lane scans k = mi*64 + lane) ---------
    float bdv[8];
    int bkv[8];
#pragma unroll
    for (int cc = 0; cc < 8; ++cc) { bdv[cc] = 1e30f; bkv[cc] = 0; }
#pragma unroll 2
    for (int mi = 0; mi < 16; ++mi) {
      const int k = (mi << 6) + lane;
      const float4 c0 = *(const float4*)(sCBNA + (k << 2));
      const float4 c1 = *(const float4*)(sCBNB + (k << 2));
      const float nnk = sNN[k];
#pragma unroll
      for (int cc = 0; cc < 8; ++cc) {
        float dot = c0.x * ef[cc][0];
        dot = fmaf(c0.y, ef[cc][1], dot);
        dot = fmaf(c0.z, ef[cc][2], dot);
        dot = fmaf(c0.w, ef[cc][3], dot);
        dot = fmaf(c1.x, ef[cc][4], dot);
        dot = fmaf(c1.y, ef[cc][5], dot);
        dot = fmaf(c1.z, ef[cc][6], dot);
        dot = fmaf(c1.w, ef[cc][7], dot);
        const float dd = fmaf(-2.f, dot, e2v[cc]) + nnk;
        if (dd < bdv[cc]) { bdv[cc] = dd; bkv[cc] = k; }  // first-min in k
      }
    }
#pragma unroll
    for (int mask = 1; mask <= 32; mask <<= 1) {
#pragma unroll
      for (int cc = 0; cc < 8; ++cc) {
        const float od = __shfl_xor(bdv[cc], mask);
        const int ok = __shfl_xor(bkv[cc], mask);
        const bool take = (od < bdv[cc]) || (od == bdv[cc] && ok < bkv[cc]);
        bdv[cc] = take ? od : bdv[cc];
        bkv[cc] = take ? ok : bkv[cc];
      }
    }
    if (lane == 0) {
      float* ip = idxout + (size_t)(nq * Bn + b) * Tn + tcol;
      float4 iv0, iv1;
      iv0.x = (float)bkv[0]; iv0.y = (float)bkv[1];
      iv0.z = (float)bkv[2]; iv0.w = (float)bkv[3];
      iv1.x = (float)bkv[4]; iv1.y = (float)bkv[5];
      iv1.z = (float)bkv[6]; iv1.w = (float)bkv[7];
      *(float4*)ip = iv0;
      *(float4*)(ip + 4) = iv1;
    }

    // ---- gather raw codebook rows (uniform broadcast reads) --------------
    float zq[8][8];
#pragma unroll
    for (int cc = 0; cc < 8; ++cc) {
      const float4 q0 = *(const float4*)(sCBR + (bkv[cc] << 3));
      const float4 q1 = *(const float4*)(sCBR + (bkv[cc] << 3) + 4);
      zq[cc][0] = q0.x; zq[cc][1] = q0.y; zq[cc][2] = q0.z; zq[cc][3] = q0.w;
      zq[cc][4] = q1.x; zq[cc][5] = q1.y; zq[cc][6] = q1.z; zq[cc][7] = q1.w;
    }

    // ---- out_proj (transposed weights) + residual update -----------------
#pragma unroll
    for (int j = 0; j < 4; ++j) {
      float acc[4][8];
#pragma unroll
      for (int i = 0; i < 4; ++i)
#pragma unroll
        for (int cc = 0; cc < 8; ++cc) acc[i][cc] = 0.f;
#pragma unroll
      for (int c = 0; c < 8; ++c) {
        const float4 wv = *(const float4*)(sWoT + (c << 10) + (j << 8) + (lane << 2));
#pragma unroll
        for (int cc = 0; cc < 8; ++cc) {
          acc[0][cc] = fmaf(wv.x, zq[cc][c], acc[0][cc]);
          acc[1][cc] = fmaf(wv.y, zq[cc][c], acc[1][cc]);
          acc[2][cc] = fmaf(wv.z, zq[cc][c], acc[2][cc]);
          acc[3][cc] = fmaf(wv.w, zq[cc][c], acc[3][cc]);
        }
      }
      const float4 bov = *(const float4*)(sBO + (j << 8) + (lane << 2));
#pragma unroll
      for (int i = 0; i < 4; ++i) {
        const float bod = (i == 0) ? bov.x : (i == 1) ? bov.y : (i == 2) ? bov.z : bov.w;
#pragma unroll
        for (int cc = 0; cc < 8; ++cc) {
          const float zo = acc[i][cc] + bod;
          r[cc][(j << 2) + i] = fmaf(-m[cc], zo, r[cc][(j << 2) + i]);
        }
      }
    }
  }  // nq

  // ---- final: qout = (z - residual) * mask --------------------------------
#pragma unroll
  for (int j = 0; j < 4; ++j) {
#pragma unroll
    for (int i = 0; i < 4; ++i) {
      const int d = (j << 8) + (lane << 2) + i;
      const float* zp = z + zb + (size_t)d * Tn + tcol;
      const float4 a0 = *(const float4*)zp;
      const float4 a1 = *(const float4*)(zp + 4);
      const int q = (j << 2) + i;
      float4 o0, o1;
      o0.x = (a0.x - r[0][q]) * m[0];
      o0.y = (a0.y - r[1][q]) * m[1];
      o0.z = (a0.z - r[2][q]) * m[2];
      o0.w = (a0.w - r[3][q]) * m[3];
      o1.x = (a1.x - r[4][q]) * m[4];
      o1.y = (a1.y - r[5][q]) * m[5];
      o1.z = (a1.z - r[6][q]) * m[6];
      o1.w = (a1.w - r[7][q]) * m[7];
      float* op = qout + zb + (size_t)d * Tn + tcol;
      *(float4*)op = o0;
      *(float4*)(op + 4) = o1;
    }
  }
}

extern "C" void kernel_launch(void* const* d_in, const int* in_sizes, int n_in,
                              void* d_out, int out_size, void* d_ws, size_t ws_size,
                              hipStream_t stream) {
  const float* z = (const float*)d_in[0];
  const int* input_length = (const int*)d_in[1];
  const float* W_in = (const float*)d_in[2];
  const float* b_in = (const float*)d_in[3];
  const float* W_out = (const float*)d_in[4];
  const float* b_out = (const float*)d_in[5];
  const float* codebooks = (const float*)d_in[6];
  float* out = (float*)d_out;

  float* wsf = (float*)d_ws;
  float* cbnA = wsf;                              // 32*1024*4 = 131072
  float* cbnB = cbnA + (size_t)NQn * Kn * 4;      // 131072
  float* n2 = cbnB + (size_t)NQn * Kn * 4;        // 32768
  float* wot = n2 + (size_t)NQn * Kn;             // 262144
  int* midx = (int*)(wot + (size_t)NQn * CDn * Dn);

  prep_cbn_kernel<<<(NQn * Kn + 255) / 256, 256, 0, stream>>>(codebooks, cbnA, cbnB, n2);
  prep_wot_kernel<<<(NQn * Dn * CDn + 255) / 256, 256, 0, stream>>>(W_out, wot);
  prep_midx_kernel<<<NQn, 64, 0, stream>>>(b_in, cbnA, cbnB, n2, midx);
  rvq_main_kernel<<<(Bn * Tn) / 64, 512, 0, stream>>>(
      z, input_length, W_in, b_in, wot, b_out, codebooks, cbnA, cbnB, n2, midx, out);
}

// Round 4
// 1482.512 us; speedup vs baseline: 1.7826x; 1.1777x over previous
//
#include <hip/hip_runtime.h>
#include <math.h>

constexpr int Bn = 8, Dn = 1024, Tn = 4096, NQn = 32, Kn = 1024, CDn = 8;
constexpr float EPSF = 1e-12f;

// ---- prepass 1: normalized codebooks as half-tables + squared norms -------
__global__ void prep_cbn_kernel(const float* __restrict__ cb,
                                float* __restrict__ cbnA,
                                float* __restrict__ cbnB,
                                float* __restrict__ n2) {
  const int idx = blockIdx.x * 256 + threadIdx.x;  // nq*K + k
  if (idx >= NQn * Kn) return;
  const float* row = cb + (size_t)idx * CDn;
  float v[8];
#pragma unroll
  for (int c = 0; c < 8; ++c) v[c] = row[c];
  float s = 0.f;
#pragma unroll
  for (int c = 0; c < 8; ++c) s += v[c] * v[c];
  const float den = fmaxf(sqrtf(s), EPSF);
  float nv[8];
#pragma unroll
  for (int c = 0; c < 8; ++c) nv[c] = v[c] / den;
  float s2 = 0.f;
#pragma unroll
  for (int c = 0; c < 8; ++c) s2 += nv[c] * nv[c];
#pragma unroll
  for (int c = 0; c < 4; ++c) cbnA[idx * 4 + c] = nv[c];
#pragma unroll
  for (int c = 0; c < 4; ++c) cbnB[idx * 4 + c] = nv[c + 4];
  n2[idx] = s2;
}

// ---- prepass 1b: transpose W_out [nq][d][c] -> [nq][c][d] -----------------
__global__ void prep_wot_kernel(const float* __restrict__ wo,
                                float* __restrict__ wot) {
  const int id = blockIdx.x * 256 + threadIdx.x;  // nq*8192 + d*8 + c
  if (id >= NQn * Dn * CDn) return;
  const int nq = id >> 13;
  const int rem = id & 8191;
  const int d = rem >> 3;
  const int c = rem & 7;
  wot[nq * 8192 + c * 1024 + d] = wo[id];
}

// ---- prepass 2: argmin index for fully-masked positions -------------------
__global__ void prep_midx_kernel(const float* __restrict__ b_in,
                                 const float* __restrict__ cbnA,
                                 const float* __restrict__ cbnB,
                                 const float* __restrict__ n2,
                                 int* __restrict__ midx) {
  const int nq = blockIdx.x;
  const int lane = threadIdx.x;  // 64 threads = 1 wave
  const float* bi = b_in + nq * CDn;
  float ze[8];
#pragma unroll
  for (int c = 0; c < 8; ++c) ze[c] = bi[c];
  float s = 0.f;
#pragma unroll
  for (int c = 0; c < 8; ++c) s += ze[c] * ze[c];
  const float den = fmaxf(sqrtf(s), EPSF);
  float enc[8];
#pragma unroll
  for (int c = 0; c < 8; ++c) enc[c] = ze[c] / den;
  float e2 = 0.f;
#pragma unroll
  for (int c = 0; c < 8; ++c) e2 += enc[c] * enc[c];

  const float* CA = cbnA + (size_t)nq * Kn * 4;
  const float* CB = cbnB + (size_t)nq * Kn * 4;
  const float* NN = n2 + (size_t)nq * Kn;
  float bd = 1e30f;
  int bk = 0;
#pragma unroll 4
  for (int mi = 0; mi < 16; ++mi) {
    const int k = (mi << 6) + lane;
    const float4 c0 = *(const float4*)(CA + (k << 2));
    const float4 c1 = *(const float4*)(CB + (k << 2));
    const float nnk = NN[k];
    float dot = c0.x * enc[0];
    dot = fmaf(c0.y, enc[1], dot);
    dot = fmaf(c0.z, enc[2], dot);
    dot = fmaf(c0.w, enc[3], dot);
    dot = fmaf(c1.x, enc[4], dot);
    dot = fmaf(c1.y, enc[5], dot);
    dot = fmaf(c1.z, enc[6], dot);
    dot = fmaf(c1.w, enc[7], dot);
    const float dd = fmaf(-2.f, dot, e2) + nnk;
    if (dd < bd) { bd = dd; bk = k; }
  }
#pragma unroll
  for (int mask = 1; mask <= 32; mask <<= 1) {
    const float od = __shfl_xor(bd, mask);
    const int ok = __shfl_xor(bk, mask);
    const bool take = (od < bd) || (od == bd && ok < bk);
    bd = take ? od : bd;
    bk = take ? ok : bk;
  }
  if (lane == 0) midx[nq] = bk;
}

// ---- masked-region fill: qout=0, idx=midx for t >= ceil(len/4)*4 ----------
__global__ void fill_masked_kernel(const int* __restrict__ lenp,
                                   const int* __restrict__ midx,
                                   float* __restrict__ out) {
  const int blk = blockIdx.x;  // 8 b x 64 chunks of 64 t
  const int b = blk >> 6;
  const int tstart = (blk & 63) << 6;
  const int tid = threadIdx.x;
  float* qout = out;
  float* idxout = out + (size_t)Bn * Dn * Tn;
  float* lenout = idxout + (size_t)NQn * Bn * Tn;
  const int len = lenp[b];
  if (blk == 0 && tid < 8) lenout[tid] = (float)lenp[tid];
  const int ag4 = ((len + 3) >> 2) << 2;  // first masked t (4-aligned)
  if (tstart + 63 < ag4) return;          // chunk fully active
  const size_t zb = (size_t)b * Dn * Tn;
  float4 zv; zv.x = 0.f; zv.y = 0.f; zv.z = 0.f; zv.w = 0.f;
  // qout zeros: 1024 d x 16 quads
#pragma unroll 4
  for (int it = 0; it < 64; ++it) {
    const int idx = (it << 8) + tid;
    const int d = idx >> 4;
    const int t = tstart + ((idx & 15) << 2);
    if (t >= ag4) *(float4*)(qout + zb + (size_t)d * Tn + t) = zv;
  }
  // idx fills: 32 nq x 16 quads
#pragma unroll
  for (int it = 0; it < 2; ++it) {
    const int idx = (it << 8) + tid;
    const int nq = idx >> 4;
    const int t = tstart + ((idx & 15) << 2);
    if (t >= ag4) {
      const float v = (float)midx[nq];
      float4 iv; iv.x = v; iv.y = v; iv.z = v; iv.w = v;
      *(float4*)(idxout + (size_t)(nq * Bn + b) * Tn + t) = iv;
    }
  }
}

// ---------------- main kernel ---------------------------------------------
// block = 512 thr = 8 waves; each wave owns ONE active group of 4 t-columns,
// assigned densely via device-side prefix over ceil(len_b/4). LDS holds only
// W_in / W_outT / b_out / b_in (69 KB -> 2 blocks/CU). Argmin tables and raw
// codebook gather read from global (L2-resident, shared, read-only).
__global__ __launch_bounds__(512, 4) void rvq_main_kernel(
    const float* __restrict__ z, const int* __restrict__ lenp,
    const float* __restrict__ W_in, const float* __restrict__ b_in,
    const float* __restrict__ wotg, const float* __restrict__ b_out,
    const float* __restrict__ cbraw, const float* __restrict__ cbnAg,
    const float* __restrict__ cbnBg, const float* __restrict__ n2g,
    float* __restrict__ out) {
  __shared__ __align__(16) float sWi[8192];   // [8 c][1024 d]
  __shared__ __align__(16) float sWoT[8192];  // [8 c][1024 d]
  __shared__ __align__(16) float sBO[1024];
  __shared__ __align__(16) float sBIall[256];

  const int tid = threadIdx.x;
  const int lane = tid & 63;
  const int w = tid >> 6;

  // ---- active-group packing ----------------------------------------------
  int pre[9];
  pre[0] = 0;
#pragma unroll
  for (int bb = 0; bb < 8; ++bb) pre[bb + 1] = pre[bb] + ((lenp[bb] + 3) >> 2);
  const int total = pre[8];
  const int g = blockIdx.x * 8 + w;
  if (blockIdx.x * 8 >= total) return;  // whole block idle
  const bool active = (g < total);

  int b = 0, tg = 0, len = 0;
  if (active) {
    while (g >= pre[b + 1]) ++b;
    tg = g - pre[b];
    len = lenp[b];
  }
  const int tcol = tg << 2;
  const size_t zb = (size_t)b * Dn * Tn;

  float* qout = out;
  float* idxout = out + (size_t)Bn * Dn * Tn;

  float m[4];
#pragma unroll
  for (int cc = 0; cc < 4; ++cc) m[cc] = (tcol + cc < len) ? 1.0f : 0.0f;

  // ---- init residual = z * mask ------------------------------------------
  float r[4][16];
  if (active) {
#pragma unroll
    for (int j = 0; j < 4; ++j) {
#pragma unroll
      for (int i = 0; i < 4; ++i) {
        const int d = (j << 8) + (lane << 2) + i;
        const float4 a0 = *(const float4*)(z + zb + (size_t)d * Tn + tcol);
        const int q = (j << 2) + i;
        r[0][q] = a0.x * m[0]; r[1][q] = a0.y * m[1];
        r[2][q] = a0.z * m[2]; r[3][q] = a0.w * m[3];
      }
    }
  }

  const int b0 = lane & 1, b1 = (lane >> 1) & 1, b2 = (lane >> 2) & 1;

#pragma unroll 1
  for (int nq = 0; nq < NQn; ++nq) {
    // ---- stage W tables into LDS (whole block) ---------------------------
    if (nq) __syncthreads();
    {
      const float4* Wi4 = (const float4*)(W_in + (size_t)nq * 8192);
      const float4* WT4 = (const float4*)(wotg + (size_t)nq * 8192);
      const float4* BO4 = (const float4*)(b_out + (size_t)nq * 1024);
#pragma unroll
      for (int qq = 0; qq < 4; ++qq) {
        const int p = tid + (qq << 9);
        ((float4*)sWi)[p] = Wi4[p];
        ((float4*)sWoT)[p] = WT4[p];
      }
      if (tid < 256) ((float4*)sBO)[tid] = BO4[tid];
      if (nq == 0 && tid < 64) ((float4*)sBIall)[tid] = ((const float4*)b_in)[tid];
    }
    __syncthreads();
    if (!active) continue;

    // ---- in_proj: per-lane partials over its 16 d's, all 8 channels ------
    float part[4][8];
#pragma unroll
    for (int cc = 0; cc < 4; ++cc)
#pragma unroll
      for (int c = 0; c < 8; ++c) part[cc][c] = 0.f;
#pragma unroll
    for (int c = 0; c < 8; ++c) {
#pragma unroll
      for (int j = 0; j < 4; ++j) {
        const float4 wv = *(const float4*)(sWi + (c << 10) + (j << 8) + (lane << 2));
#pragma unroll
        for (int cc = 0; cc < 4; ++cc) {
          part[cc][c] = fmaf(wv.x, r[cc][(j << 2) + 0], part[cc][c]);
          part[cc][c] = fmaf(wv.y, r[cc][(j << 2) + 1], part[cc][c]);
          part[cc][c] = fmaf(wv.z, r[cc][(j << 2) + 2], part[cc][c]);
          part[cc][c] = fmaf(wv.w, r[cc][(j << 2) + 3], part[cc][c]);
        }
      }
    }
    const float biv = sBIall[(nq << 3) + (lane & 7)];

    // ---- transpose-reduce 8 partials across 64 lanes; normalize ----------
    float ef[4][8], e2v[4];
#pragma unroll
    for (int cc = 0; cc < 4; ++cc) {
      float u0, u1, u2, u3, v0, v1, t;
      {
        float k0 = b0 ? part[cc][1] : part[cc][0];
        float s0 = b0 ? part[cc][0] : part[cc][1];
        u0 = k0 + __shfl_xor(s0, 1);
        float k1 = b0 ? part[cc][3] : part[cc][2];
        float s1 = b0 ? part[cc][2] : part[cc][3];
        u1 = k1 + __shfl_xor(s1, 1);
        float k2 = b0 ? part[cc][5] : part[cc][4];
        float s2 = b0 ? part[cc][4] : part[cc][5];
        u2 = k2 + __shfl_xor(s2, 1);
        float k3 = b0 ? part[cc][7] : part[cc][6];
        float s3 = b0 ? part[cc][6] : part[cc][7];
        u3 = k3 + __shfl_xor(s3, 1);
      }
      v0 = (b1 ? u1 : u0) + __shfl_xor(b1 ? u0 : u1, 2);
      v1 = (b1 ? u3 : u2) + __shfl_xor(b1 ? u2 : u3, 2);
      t = (b2 ? v1 : v0) + __shfl_xor(b2 ? v0 : v1, 4);
      t += __shfl_xor(t, 8);
      t += __shfl_xor(t, 16);
      t += __shfl_xor(t, 32);
      const float zec = t + biv;  // lane holds z_e[c = lane&7]
      float nn = zec * zec;
      nn += __shfl_xor(nn, 1);
      nn += __shfl_xor(nn, 2);
      nn += __shfl_xor(nn, 4);
      const float den = fmaxf(sqrtf(nn), EPSF);
      const float ec = zec / den;
      float e2 = ec * ec;
      e2 += __shfl_xor(e2, 1);
      e2 += __shfl_xor(e2, 2);
      e2 += __shfl_xor(e2, 4);
      e2v[cc] = e2;
#pragma unroll
      for (int c = 0; c < 8; ++c) ef[cc][c] = __shfl(ec, c);
    }

    // ---- dist + argmin over K=1024 from GLOBAL (L2) ----------------------
    const float* CA = cbnAg + (size_t)nq * Kn * 4;
    const float* CB = cbnBg + (size_t)nq * Kn * 4;
    const float* NN = n2g + (size_t)nq * Kn;
    float bdv[4];
    int bkv[4];
#pragma unroll
    for (int cc = 0; cc < 4; ++cc) { bdv[cc] = 1e30f; bkv[cc] = 0; }
#pragma unroll 4
    for (int mi = 0; mi < 16; ++mi) {
      const int k = (mi << 6) + lane;
      const float4 c0 = *(const float4*)(CA + (k << 2));
      const float4 c1 = *(const float4*)(CB + (k << 2));
      const float nnk = NN[k];
#pragma unroll
      for (int cc = 0; cc < 4; ++cc) {
        float dot = c0.x * ef[cc][0];
        dot = fmaf(c0.y, ef[cc][1], dot);
        dot = fmaf(c0.z, ef[cc][2], dot);
        dot = fmaf(c0.w, ef[cc][3], dot);
        dot = fmaf(c1.x, ef[cc][4], dot);
        dot = fmaf(c1.y, ef[cc][5], dot);
        dot = fmaf(c1.z, ef[cc][6], dot);
        dot = fmaf(c1.w, ef[cc][7], dot);
        const float dd = fmaf(-2.f, dot, e2v[cc]) + nnk;
        if (dd < bdv[cc]) { bdv[cc] = dd; bkv[cc] = k; }  // first-min in k
      }
    }
#pragma unroll
    for (int mask = 1; mask <= 32; mask <<= 1) {
#pragma unroll
      for (int cc = 0; cc < 4; ++cc) {
        const float od = __shfl_xor(bdv[cc], mask);
        const int ok = __shfl_xor(bkv[cc], mask);
        const bool take = (od < bdv[cc]) || (od == bdv[cc] && ok < bkv[cc]);
        bdv[cc] = take ? od : bdv[cc];
        bkv[cc] = take ? ok : bkv[cc];
      }
    }
    if (lane == 0) {
      float4 iv;
      iv.x = (float)bkv[0]; iv.y = (float)bkv[1];
      iv.z = (float)bkv[2]; iv.w = (float)bkv[3];
      *(float4*)(idxout + (size_t)(nq * Bn + b) * Tn + tcol) = iv;
    }

    // ---- gather raw codebook rows from global (uniform addr) -------------
    const float* CBR = cbraw + (size_t)nq * 8192;
    float zq[4][8];
#pragma unroll
    for (int cc = 0; cc < 4; ++cc) {
      const float4 q0 = *(const float4*)(CBR + (bkv[cc] << 3));
      const float4 q1 = *(const float4*)(CBR + (bkv[cc] << 3) + 4);
      zq[cc][0] = q0.x; zq[cc][1] = q0.y; zq[cc][2] = q0.z; zq[cc][3] = q0.w;
      zq[cc][4] = q1.x; zq[cc][5] = q1.y; zq[cc][6] = q1.z; zq[cc][7] = q1.w;
    }

    // ---- out_proj (transposed weights) + residual update -----------------
#pragma unroll
    for (int j = 0; j < 4; ++j) {
      float acc[4][4];
#pragma unroll
      for (int i = 0; i < 4; ++i)
#pragma unroll
        for (int cc = 0; cc < 4; ++cc) acc[i][cc] = 0.f;
#pragma unroll
      for (int c = 0; c < 8; ++c) {
        const float4 wv = *(const float4*)(sWoT + (c << 10) + (j << 8) + (lane << 2));
#pragma unroll
        for (int cc = 0; cc < 4; ++cc) {
          acc[0][cc] = fmaf(wv.x, zq[cc][c], acc[0][cc]);
          acc[1][cc] = fmaf(wv.y, zq[cc][c], acc[1][cc]);
          acc[2][cc] = fmaf(wv.z, zq[cc][c], acc[2][cc]);
          acc[3][cc] = fmaf(wv.w, zq[cc][c], acc[3][cc]);
        }
      }
      const float4 bov = *(const float4*)(sBO + (j << 8) + (lane << 2));
#pragma unroll
      for (int i = 0; i < 4; ++i) {
        const float bod = (i == 0) ? bov.x : (i == 1) ? bov.y : (i == 2) ? bov.z : bov.w;
#pragma unroll
        for (int cc = 0; cc < 4; ++cc) {
          const float zo = acc[i][cc] + bod;
          r[cc][(j << 2) + i] = fmaf(-m[cc], zo, r[cc][(j << 2) + i]);
        }
      }
    }
  }  // nq

  if (!active) return;

  // ---- final: qout = (z - residual) * mask --------------------------------
#pragma unroll
  for (int j = 0; j < 4; ++j) {
#pragma unroll
    for (int i = 0; i < 4; ++i) {
      const int d = (j << 8) + (lane << 2) + i;
      const float4 a0 = *(const float4*)(z + zb + (size_t)d * Tn + tcol);
      const int q = (j << 2) + i;
      float4 o0;
      o0.x = (a0.x - r[0][q]) * m[0];
      o0.y = (a0.y - r[1][q]) * m[1];
      o0.z = (a0.z - r[2][q]) * m[2];
      o0.w = (a0.w - r[3][q]) * m[3];
      *(float4*)(qout + zb + (size_t)d * Tn + tcol) = o0;
    }
  }
}

extern "C" void kernel_launch(void* const* d_in, const int* in_sizes, int n_in,
                              void* d_out, int out_size, void* d_ws, size_t ws_size,
                              hipStream_t stream) {
  const float* z = (const float*)d_in[0];
  const int* input_length = (const int*)d_in[1];
  const float* W_in = (const float*)d_in[2];
  const float* b_in = (const float*)d_in[3];
  const float* W_out = (const float*)d_in[4];
  const float* b_out = (const float*)d_in[5];
  const float* codebooks = (const float*)d_in[6];
  float* out = (float*)d_out;

  float* wsf = (float*)d_ws;
  float* cbnA = wsf;                          // 32*1024*4 floats
  float* cbnB = cbnA + (size_t)NQn * Kn * 4;  // 32*1024*4
  float* n2 = cbnB + (size_t)NQn * Kn * 4;    // 32*1024
  float* wot = n2 + (size_t)NQn * Kn;         // 32*8192
  int* midx = (int*)(wot + (size_t)NQn * CDn * Dn);

  prep_cbn_kernel<<<(NQn * Kn + 255) / 256, 256, 0, stream>>>(codebooks, cbnA, cbnB, n2);
  prep_wot_kernel<<<(NQn * Dn * CDn + 255) / 256, 256, 0, stream>>>(W_out, wot);
  prep_midx_kernel<<<NQn, 64, 0, stream>>>(b_in, cbnA, cbnB, n2, midx);
  fill_masked_kernel<<<8 * 64, 256, 0, stream>>>(input_length, midx, out);
  rvq_main_kernel<<<(Bn * Tn / 4) / 8, 512, 0, stream>>>(
      z, input_length, W_in, b_in, wot, b_out, codebooks, cbnA, cbnB, n2, out);
}

// Round 5
// 1158.959 us; speedup vs baseline: 2.2803x; 1.2792x over previous
//
#include <hip/hip_runtime.h>
#include <math.h>

constexpr int Bn = 8, Dn = 1024, Tn = 4096, NQn = 32, Kn = 1024, CDn = 8;
constexpr float EPSF = 1e-12f;

// ---- prepass 1: normalized codebooks as half-tables + squared norms -------
__global__ void prep_cbn_kernel(const float* __restrict__ cb,
                                float* __restrict__ cbnA,
                                float* __restrict__ cbnB,
                                float* __restrict__ n2) {
  const int idx = blockIdx.x * 256 + threadIdx.x;  // nq*K + k
  if (idx >= NQn * Kn) return;
  const float* row = cb + (size_t)idx * CDn;
  float v[8];
#pragma unroll
  for (int c = 0; c < 8; ++c) v[c] = row[c];
  float s = 0.f;
#pragma unroll
  for (int c = 0; c < 8; ++c) s += v[c] * v[c];
  const float den = fmaxf(sqrtf(s), EPSF);
  float nv[8];
#pragma unroll
  for (int c = 0; c < 8; ++c) nv[c] = v[c] / den;
  float s2 = 0.f;
#pragma unroll
  for (int c = 0; c < 8; ++c) s2 += nv[c] * nv[c];
#pragma unroll
  for (int c = 0; c < 4; ++c) cbnA[idx * 4 + c] = nv[c];
#pragma unroll
  for (int c = 0; c < 4; ++c) cbnB[idx * 4 + c] = nv[c + 4];
  n2[idx] = s2;
}

// ---- prepass 1b: transpose W_out [nq][d][c] -> [nq][c][d] -----------------
__global__ void prep_wot_kernel(const float* __restrict__ wo,
                                float* __restrict__ wot) {
  const int id = blockIdx.x * 256 + threadIdx.x;  // nq*8192 + d*8 + c
  if (id >= NQn * Dn * CDn) return;
  const int nq = id >> 13;
  const int rem = id & 8191;
  const int d = rem >> 3;
  const int c = rem & 7;
  wot[nq * 8192 + c * 1024 + d] = wo[id];
}

// ---- prepass 2: argmin index for fully-masked positions -------------------
__global__ void prep_midx_kernel(const float* __restrict__ b_in,
                                 const float* __restrict__ cbnA,
                                 const float* __restrict__ cbnB,
                                 const float* __restrict__ n2,
                                 int* __restrict__ midx) {
  const int nq = blockIdx.x;
  const int lane = threadIdx.x;  // 64 threads = 1 wave
  const float* bi = b_in + nq * CDn;
  float ze[8];
#pragma unroll
  for (int c = 0; c < 8; ++c) ze[c] = bi[c];
  float s = 0.f;
#pragma unroll
  for (int c = 0; c < 8; ++c) s += ze[c] * ze[c];
  const float den = fmaxf(sqrtf(s), EPSF);
  float enc[8];
#pragma unroll
  for (int c = 0; c < 8; ++c) enc[c] = ze[c] / den;
  float e2 = 0.f;
#pragma unroll
  for (int c = 0; c < 8; ++c) e2 += enc[c] * enc[c];

  const float* CA = cbnA + (size_t)nq * Kn * 4;
  const float* CB = cbnB + (size_t)nq * Kn * 4;
  const float* NN = n2 + (size_t)nq * Kn;
  float bd = 1e30f;
  int bk = 0;
#pragma unroll 4
  for (int mi = 0; mi < 16; ++mi) {
    const int k = (mi << 6) + lane;
    const float4 c0 = *(const float4*)(CA + (k << 2));
    const float4 c1 = *(const float4*)(CB + (k << 2));
    const float nnk = NN[k];
    float dot = c0.x * enc[0];
    dot = fmaf(c0.y, enc[1], dot);
    dot = fmaf(c0.z, enc[2], dot);
    dot = fmaf(c0.w, enc[3], dot);
    dot = fmaf(c1.x, enc[4], dot);
    dot = fmaf(c1.y, enc[5], dot);
    dot = fmaf(c1.z, enc[6], dot);
    dot = fmaf(c1.w, enc[7], dot);
    const float dd = fmaf(-2.f, dot, e2) + nnk;
    if (dd < bd) { bd = dd; bk = k; }
  }
#pragma unroll
  for (int mask = 1; mask <= 32; mask <<= 1) {
    const float od = __shfl_xor(bd, mask);
    const int ok = __shfl_xor(bk, mask);
    const bool take = (od < bd) || (od == bd && ok < bk);
    bd = take ? od : bd;
    bk = take ? ok : bk;
  }
  if (lane == 0) midx[nq] = bk;
}

// ---- masked-region fill: qout=0, idx=midx for t >= ceil(len/4)*4 ----------
__global__ void fill_masked_kernel(const int* __restrict__ lenp,
                                   const int* __restrict__ midx,
                                   float* __restrict__ out) {
  const int blk = blockIdx.x;  // 8 b x 64 chunks of 64 t
  const int b = blk >> 6;
  const int tstart = (blk & 63) << 6;
  const int tid = threadIdx.x;
  float* qout = out;
  float* idxout = out + (size_t)Bn * Dn * Tn;
  float* lenout = idxout + (size_t)NQn * Bn * Tn;
  const int len = lenp[b];
  if (blk == 0 && tid < 8) lenout[tid] = (float)lenp[tid];
  const int ag4 = ((len + 3) >> 2) << 2;  // first masked t (4-aligned)
  if (tstart + 63 < ag4) return;          // chunk fully active
  const size_t zb = (size_t)b * Dn * Tn;
  float4 zv; zv.x = 0.f; zv.y = 0.f; zv.z = 0.f; zv.w = 0.f;
  // qout zeros: 1024 d x 16 quads
#pragma unroll 4
  for (int it = 0; it < 64; ++it) {
    const int idx = (it << 8) + tid;
    const int d = idx >> 4;
    const int t = tstart + ((idx & 15) << 2);
    if (t >= ag4) *(float4*)(qout + zb + (size_t)d * Tn + t) = zv;
  }
  // idx fills: 32 nq x 16 quads
#pragma unroll
  for (int it = 0; it < 2; ++it) {
    const int idx = (it << 8) + tid;
    const int nq = idx >> 4;
    const int t = tstart + ((idx & 15) << 2);
    if (t >= ag4) {
      const float v = (float)midx[nq];
      float4 iv; iv.x = v; iv.y = v; iv.z = v; iv.w = v;
      *(float4*)(idxout + (size_t)(nq * Bn + b) * Tn + t) = iv;
    }
  }
}

// ---------------- main kernel ---------------------------------------------
// block = 512 thr = 8 waves; each wave owns ONE active group of 4 t-columns,
// assigned densely via device-side prefix over ceil(len_b/4). LDS holds only
// W_in / W_outT / b_out / b_in (69 KB -> 2 blocks/CU). Argmin tables and raw
// codebook gather read from global (L2-resident, shared, read-only).
// NOTE: (512,2) not (512,4) — the latter compiles to a 64-VGPR budget (CUDA
// min-blocks semantics) and spills ~4 GB of scratch traffic per dispatch.
__global__ __launch_bounds__(512, 2) void rvq_main_kernel(
    const float* __restrict__ z, const int* __restrict__ lenp,
    const float* __restrict__ W_in, const float* __restrict__ b_in,
    const float* __restrict__ wotg, const float* __restrict__ b_out,
    const float* __restrict__ cbraw, const float* __restrict__ cbnAg,
    const float* __restrict__ cbnBg, const float* __restrict__ n2g,
    float* __restrict__ out) {
  __shared__ __align__(16) float sWi[8192];   // [8 c][1024 d]
  __shared__ __align__(16) float sWoT[8192];  // [8 c][1024 d]
  __shared__ __align__(16) float sBO[1024];
  __shared__ __align__(16) float sBIall[256];

  const int tid = threadIdx.x;
  const int lane = tid & 63;
  const int w = tid >> 6;

  // ---- active-group packing ----------------------------------------------
  int pre[9];
  pre[0] = 0;
#pragma unroll
  for (int bb = 0; bb < 8; ++bb) pre[bb + 1] = pre[bb] + ((lenp[bb] + 3) >> 2);
  const int total = pre[8];
  const int g = blockIdx.x * 8 + w;
  if (blockIdx.x * 8 >= total) return;  // whole block idle
  const bool active = (g < total);

  int b = 0, tg = 0, len = 0;
  if (active) {
    while (g >= pre[b + 1]) ++b;
    tg = g - pre[b];
    len = lenp[b];
  }
  const int tcol = tg << 2;
  const size_t zb = (size_t)b * Dn * Tn;

  float* qout = out;
  float* idxout = out + (size_t)Bn * Dn * Tn;

  float m[4];
#pragma unroll
  for (int cc = 0; cc < 4; ++cc) m[cc] = (tcol + cc < len) ? 1.0f : 0.0f;

  // ---- init residual = z * mask ------------------------------------------
  float r[4][16];
  if (active) {
#pragma unroll
    for (int j = 0; j < 4; ++j) {
#pragma unroll
      for (int i = 0; i < 4; ++i) {
        const int d = (j << 8) + (lane << 2) + i;
        const float4 a0 = *(const float4*)(z + zb + (size_t)d * Tn + tcol);
        const int q = (j << 2) + i;
        r[0][q] = a0.x * m[0]; r[1][q] = a0.y * m[1];
        r[2][q] = a0.z * m[2]; r[3][q] = a0.w * m[3];
      }
    }
  }

  const int b0 = lane & 1, b1 = (lane >> 1) & 1, b2 = (lane >> 2) & 1;

#pragma unroll 1
  for (int nq = 0; nq < NQn; ++nq) {
    // ---- stage W tables into LDS (whole block) ---------------------------
    if (nq) __syncthreads();
    {
      const float4* Wi4 = (const float4*)(W_in + (size_t)nq * 8192);
      const float4* WT4 = (const float4*)(wotg + (size_t)nq * 8192);
      const float4* BO4 = (const float4*)(b_out + (size_t)nq * 1024);
#pragma unroll
      for (int qq = 0; qq < 4; ++qq) {
        const int p = tid + (qq << 9);
        ((float4*)sWi)[p] = Wi4[p];
        ((float4*)sWoT)[p] = WT4[p];
      }
      if (tid < 256) ((float4*)sBO)[tid] = BO4[tid];
      if (nq == 0 && tid < 64) ((float4*)sBIall)[tid] = ((const float4*)b_in)[tid];
    }
    __syncthreads();
    if (!active) continue;

    // ---- in_proj: per-lane partials over its 16 d's, all 8 channels ------
    float part[4][8];
#pragma unroll
    for (int cc = 0; cc < 4; ++cc)
#pragma unroll
      for (int c = 0; c < 8; ++c) part[cc][c] = 0.f;
#pragma unroll
    for (int c = 0; c < 8; ++c) {
#pragma unroll
      for (int j = 0; j < 4; ++j) {
        const float4 wv = *(const float4*)(sWi + (c << 10) + (j << 8) + (lane << 2));
#pragma unroll
        for (int cc = 0; cc < 4; ++cc) {
          part[cc][c] = fmaf(wv.x, r[cc][(j << 2) + 0], part[cc][c]);
          part[cc][c] = fmaf(wv.y, r[cc][(j << 2) + 1], part[cc][c]);
          part[cc][c] = fmaf(wv.z, r[cc][(j << 2) + 2], part[cc][c]);
          part[cc][c] = fmaf(wv.w, r[cc][(j << 2) + 3], part[cc][c]);
        }
      }
    }
    const float biv = sBIall[(nq << 3) + (lane & 7)];

    // ---- transpose-reduce 8 partials across 64 lanes; normalize ----------
    float ef[4][8], e2v[4];
#pragma unroll
    for (int cc = 0; cc < 4; ++cc) {
      float u0, u1, u2, u3, v0, v1, t;
      {
        float k0 = b0 ? part[cc][1] : part[cc][0];
        float s0 = b0 ? part[cc][0] : part[cc][1];
        u0 = k0 + __shfl_xor(s0, 1);
        float k1 = b0 ? part[cc][3] : part[cc][2];
        float s1 = b0 ? part[cc][2] : part[cc][3];
        u1 = k1 + __shfl_xor(s1, 1);
        float k2 = b0 ? part[cc][5] : part[cc][4];
        float s2 = b0 ? part[cc][4] : part[cc][5];
        u2 = k2 + __shfl_xor(s2, 1);
        float k3 = b0 ? part[cc][7] : part[cc][6];
        float s3 = b0 ? part[cc][6] : part[cc][7];
        u3 = k3 + __shfl_xor(s3, 1);
      }
      v0 = (b1 ? u1 : u0) + __shfl_xor(b1 ? u0 : u1, 2);
      v1 = (b1 ? u3 : u2) + __shfl_xor(b1 ? u2 : u3, 2);
      t = (b2 ? v1 : v0) + __shfl_xor(b2 ? v0 : v1, 4);
      t += __shfl_xor(t, 8);
      t += __shfl_xor(t, 16);
      t += __shfl_xor(t, 32);
      const float zec = t + biv;  // lane holds z_e[c = lane&7]
      float nn = zec * zec;
      nn += __shfl_xor(nn, 1);
      nn += __shfl_xor(nn, 2);
      nn += __shfl_xor(nn, 4);
      const float den = fmaxf(sqrtf(nn), EPSF);
      const float ec = zec / den;
      float e2 = ec * ec;
      e2 += __shfl_xor(e2, 1);
      e2 += __shfl_xor(e2, 2);
      e2 += __shfl_xor(e2, 4);
      e2v[cc] = e2;
#pragma unroll
      for (int c = 0; c < 8; ++c) ef[cc][c] = __shfl(ec, c);
    }

    // ---- dist + argmin over K=1024 from GLOBAL (L2) ----------------------
    const float* CA = cbnAg + (size_t)nq * Kn * 4;
    const float* CB = cbnBg + (size_t)nq * Kn * 4;
    const float* NN = n2g + (size_t)nq * Kn;
    float bdv[4];
    int bkv[4];
#pragma unroll
    for (int cc = 0; cc < 4; ++cc) { bdv[cc] = 1e30f; bkv[cc] = 0; }
#pragma unroll 4
    for (int mi = 0; mi < 16; ++mi) {
      const int k = (mi << 6) + lane;
      const float4 c0 = *(const float4*)(CA + (k << 2));
      const float4 c1 = *(const float4*)(CB + (k << 2));
      const float nnk = NN[k];
#pragma unroll
      for (int cc = 0; cc < 4; ++cc) {
        float dot = c0.x * ef[cc][0];
        dot = fmaf(c0.y, ef[cc][1], dot);
        dot = fmaf(c0.z, ef[cc][2], dot);
        dot = fmaf(c0.w, ef[cc][3], dot);
        dot = fmaf(c1.x, ef[cc][4], dot);
        dot = fmaf(c1.y, ef[cc][5], dot);
        dot = fmaf(c1.z, ef[cc][6], dot);
        dot = fmaf(c1.w, ef[cc][7], dot);
        const float dd = fmaf(-2.f, dot, e2v[cc]) + nnk;
        if (dd < bdv[cc]) { bdv[cc] = dd; bkv[cc] = k; }  // first-min in k
      }
    }
#pragma unroll
    for (int mask = 1; mask <= 32; mask <<= 1) {
#pragma unroll
      for (int cc = 0; cc < 4; ++cc) {
        const float od = __shfl_xor(bdv[cc], mask);
        const int ok = __shfl_xor(bkv[cc], mask);
        const bool take = (od < bdv[cc]) || (od == bdv[cc] && ok < bkv[cc]);
        bdv[cc] = take ? od : bdv[cc];
        bkv[cc] = take ? ok : bkv[cc];
      }
    }
    if (lane == 0) {
      float4 iv;
      iv.x = (float)bkv[0]; iv.y = (float)bkv[1];
      iv.z = (float)bkv[2]; iv.w = (float)bkv[3];
      *(float4*)(idxout + (size_t)(nq * Bn + b) * Tn + tcol) = iv;
    }

    // ---- gather raw codebook rows from global (uniform addr) -------------
    const float* CBR = cbraw + (size_t)nq * 8192;
    float zq[4][8];
#pragma unroll
    for (int cc = 0; cc < 4; ++cc) {
      const float4 q0 = *(const float4*)(CBR + (bkv[cc] << 3));
      const float4 q1 = *(const float4*)(CBR + (bkv[cc] << 3) + 4);
      zq[cc][0] = q0.x; zq[cc][1] = q0.y; zq[cc][2] = q0.z; zq[cc][3] = q0.w;
      zq[cc][4] = q1.x; zq[cc][5] = q1.y; zq[cc][6] = q1.z; zq[cc][7] = q1.w;
    }

    // ---- out_proj (transposed weights) + residual update -----------------
#pragma unroll
    for (int j = 0; j < 4; ++j) {
      float acc[4][4];
#pragma unroll
      for (int i = 0; i < 4; ++i)
#pragma unroll
        for (int cc = 0; cc < 4; ++cc) acc[i][cc] = 0.f;
#pragma unroll
      for (int c = 0; c < 8; ++c) {
        const float4 wv = *(const float4*)(sWoT + (c << 10) + (j << 8) + (lane << 2));
#pragma unroll
        for (int cc = 0; cc < 4; ++cc) {
          acc[0][cc] = fmaf(wv.x, zq[cc][c], acc[0][cc]);
          acc[1][cc] = fmaf(wv.y, zq[cc][c], acc[1][cc]);
          acc[2][cc] = fmaf(wv.z, zq[cc][c], acc[2][cc]);
          acc[3][cc] = fmaf(wv.w, zq[cc][c], acc[3][cc]);
        }
      }
      const float4 bov = *(const float4*)(sBO + (j << 8) + (lane << 2));
#pragma unroll
      for (int i = 0; i < 4; ++i) {
        const float bod = (i == 0) ? bov.x : (i == 1) ? bov.y : (i == 2) ? bov.z : bov.w;
#pragma unroll
        for (int cc = 0; cc < 4; ++cc) {
          const float zo = acc[i][cc] + bod;
          r[cc][(j << 2) + i] = fmaf(-m[cc], zo, r[cc][(j << 2) + i]);
        }
      }
    }
  }  // nq

  if (!active) return;

  // ---- final: qout = (z - residual) * mask --------------------------------
#pragma unroll
  for (int j = 0; j < 4; ++j) {
#pragma unroll
    for (int i = 0; i < 4; ++i) {
      const int d = (j << 8) + (lane << 2) + i;
      const float4 a0 = *(const float4*)(z + zb + (size_t)d * Tn + tcol);
      const int q = (j << 2) + i;
      float4 o0;
      o0.x = (a0.x - r[0][q]) * m[0];
      o0.y = (a0.y - r[1][q]) * m[1];
      o0.z = (a0.z - r[2][q]) * m[2];
      o0.w = (a0.w - r[3][q]) * m[3];
      *(float4*)(qout + zb + (size_t)d * Tn + tcol) = o0;
    }
  }
}

extern "C" void kernel_launch(void* const* d_in, const int* in_sizes, int n_in,
                              void* d_out, int out_size, void* d_ws, size_t ws_size,
                              hipStream_t stream) {
  const float* z = (const float*)d_in[0];
  const int* input_length = (const int*)d_in[1];
  const float* W_in = (const float*)d_in[2];
  const float* b_in = (const float*)d_in[3];
  const float* W_out = (const float*)d_in[4];
  const float* b_out = (const float*)d_in[5];
  const float* codebooks = (const float*)d_in[6];
  float* out = (float*)d_out;

  float* wsf = (float*)d_ws;
  float* cbnA = wsf;                          // 32*1024*4 floats
  float* cbnB = cbnA + (size_t)NQn * Kn * 4;  // 32*1024*4
  float* n2 = cbnB + (size_t)NQn * Kn * 4;    // 32*1024
  float* wot = n2 + (size_t)NQn * Kn;         // 32*8192
  int* midx = (int*)(wot + (size_t)NQn * CDn * Dn);

  prep_cbn_kernel<<<(NQn * Kn + 255) / 256, 256, 0, stream>>>(codebooks, cbnA, cbnB, n2);
  prep_wot_kernel<<<(NQn * Dn * CDn + 255) / 256, 256, 0, stream>>>(W_out, wot);
  prep_midx_kernel<<<NQn, 64, 0, stream>>>(b_in, cbnA, cbnB, n2, midx);
  fill_masked_kernel<<<8 * 64, 256, 0, stream>>>(input_length, midx, out);
  rvq_main_kernel<<<(Bn * Tn / 4) / 8, 512, 0, stream>>>(
      z, input_length, W_in, b_in, wot, b_out, codebooks, cbnA, cbnB, n2, out);
}